// Round 5
// baseline (402.281 us; speedup 1.0000x reference)
//
#include <hip/hip_runtime.h>

#define NN 100000
#define NE 600000
#define F  128
#define BN_EPS 1e-5f
#define TM 256
#define TK 32

// ---- init + detect int64 vs int32 edge_index (block 0 does detect) ----
__global__ void k_init(const unsigned* __restrict__ ei, int* __restrict__ flag,
                       int* __restrict__ cnt, float* __restrict__ colsum, float* __restrict__ colsq)
{
    int i = blockIdx.x * 256 + threadIdx.x;
    if (i <= NN) cnt[i] = 0;
    if (i < F) { colsum[i] = 0.f; colsq[i] = 0.f; }
    if (blockIdx.x == 0) {
        __shared__ int any;
        if (threadIdx.x == 0) any = 0;
        __syncthreads();
        unsigned v = ei[2 * threadIdx.x + 1];   // odd words: i64 high halves (0 if i64)
        if (v != 0u) atomicOr(&any, 1);
        __syncthreads();
        if (threadIdx.x == 0) *flag = (any == 0) ? 1 : 0;   // 1 => int64
    }
}

__global__ void k_count(const void* __restrict__ ei, const int* __restrict__ flag, int* __restrict__ cnt)
{
    int e = blockIdx.x * 256 + threadIdx.x;
    if (e >= NE) return;
    int col;
    if (*flag) col = (int)((const long long*)ei)[NE + e];
    else       col = ((const int*)ei)[NE + e];
    atomicAdd(&cnt[col], 1);
}

// ---- 3-kernel exclusive scan of cnt[0..NN] -> off[], cur[]; dinv fused ----
__global__ void k_bsum(const int* __restrict__ cnt, int* __restrict__ bsum)
{
    __shared__ int s[256];
    int b = blockIdx.x, t = threadIdx.x;
    int i = b * 256 + t;
    s[t] = (i <= NN) ? cnt[i] : 0;
    __syncthreads();
    for (int o = 128; o > 0; o >>= 1) {
        if (t < o) s[t] += s[t + o];
        __syncthreads();
    }
    if (t == 0) bsum[b] = s[0];
}

__global__ void k_bscan(const int* __restrict__ bsum, int* __restrict__ bbase)
{
    __shared__ int s[512];
    int t = threadIdx.x;
    int v = (t < 391) ? bsum[t] : 0;
    s[t] = v;
    __syncthreads();
    for (int o = 1; o < 512; o <<= 1) {
        int tmp = (t >= o) ? s[t - o] : 0;
        __syncthreads();
        s[t] += tmp;
        __syncthreads();
    }
    if (t < 391) bbase[t] = s[t] - v;   // exclusive
}

__global__ void k_offsets(const int* __restrict__ cnt, const int* __restrict__ bbase,
                          int* __restrict__ off, int* __restrict__ cur,
                          float* __restrict__ dinv)
{
    __shared__ int s[256];
    int b = blockIdx.x, t = threadIdx.x;
    int i = b * 256 + t;
    int v = (i <= NN) ? cnt[i] : 0;
    s[t] = v;
    __syncthreads();
    for (int o = 1; o < 256; o <<= 1) {
        int tmp = (t >= o) ? s[t - o] : 0;
        __syncthreads();
        s[t] += tmp;
        __syncthreads();
    }
    int excl = s[t] - v + bbase[b];
    if (i <= NN) {
        off[i] = excl;
        if (i < NN) {
            cur[i] = excl;
            float d = (float)(v + 1);           // +1 self-loop
            float r = rsqrtf(d);
            r = r * (1.5f - 0.5f * d * r * r);  // Newton refine
            dinv[i] = r;
        }
    }
}

__global__ void k_place(const void* __restrict__ ei, const int* __restrict__ flag,
                        int* __restrict__ cur, int* __restrict__ csr)
{
    int e = blockIdx.x * 256 + threadIdx.x;
    if (e >= NE) return;
    int row, col;
    if (*flag) {
        row = (int)((const long long*)ei)[e];
        col = (int)((const long long*)ei)[NE + e];
    } else {
        row = ((const int*)ei)[e];
        col = ((const int*)ei)[NE + e];
    }
    int slot = atomicAdd(&cur[col], 1);
    csr[slot] = row;
}

// ---- pull aggregation: one node per HALF-wave (32 lanes x float4 = 128 feats),
//      2 edges per VMEM instr when both halves active ----
__global__ __launch_bounds__(256) void k_agg(const float* __restrict__ x, const float* __restrict__ dinv,
                                             const int* __restrict__ off, const int* __restrict__ csr,
                                             float* __restrict__ aggx)
{
    int node = blockIdx.x * 8 + (threadIdx.x >> 5);   // 12500 blocks * 8 = 100000 exact
    int sub  = threadIdx.x & 31;
    float di = dinv[node];
    float4 v = ((const float4*)(x + (size_t)node * F))[sub];
    float ax = v.x * di, ay = v.y * di, az = v.z * di, aw = v.w * di;
    int e = off[node], e1 = off[node + 1];
    for (; e + 2 <= e1; e += 2) {
        int r0 = csr[e], r1 = csr[e + 1];
        float s0 = dinv[r0], s1 = dinv[r1];
        float4 u0 = ((const float4*)(x + (size_t)r0 * F))[sub];
        float4 u1 = ((const float4*)(x + (size_t)r1 * F))[sub];
        ax = fmaf(u0.x, s0, ax); ay = fmaf(u0.y, s0, ay);
        az = fmaf(u0.z, s0, az); aw = fmaf(u0.w, s0, aw);
        ax = fmaf(u1.x, s1, ax); ay = fmaf(u1.y, s1, ay);
        az = fmaf(u1.z, s1, az); aw = fmaf(u1.w, s1, aw);
    }
    if (e < e1) {
        int r = csr[e]; float s = dinv[r];
        float4 u = ((const float4*)(x + (size_t)r * F))[sub];
        ax = fmaf(u.x, s, ax); ay = fmaf(u.y, s, ay);
        az = fmaf(u.z, s, az); aw = fmaf(u.w, s, aw);
    }
    float4 o; o.x = ax * di; o.y = ay * di; o.z = az * di; o.w = aw * di;
    ((float4*)(aggx + (size_t)node * F))[sub] = o;
}

// ---- GEMM: blockIdx.y==0 : r = relu(aggx@W + b) in-place into aggx, + BN partials
//            blockIdx.y==1 : out = x@Wr + br
// TM=256 rows, 128 cols, microtile 16 rows x 8 cols (strided rows: ty + i*16).
// Register prefetch of next chunk (global->reg during compute, reg->LDS after
// barrier) hides staging latency. At stride 36 keeps A-reads conflict-free.
__global__ __launch_bounds__(256) void k_gemm2(
    float* __restrict__ A, const float* __restrict__ X,
    const float* __restrict__ W, const float* __restrict__ Wr,
    const float* __restrict__ bias, const float* __restrict__ biasr,
    float* __restrict__ out, float* __restrict__ colsum, float* __restrict__ colsq)
{
    __shared__ float At[TM][36];    // 36 KB (stride 36: 16B-aligned rows, 2-way max on reads)
    __shared__ float Wt[TK][F];     // 16 KB

    const int tid = threadIdx.x;
    const int tx = tid & 15;        // cols tx*8 .. tx*8+7
    const int ty = tid >> 4;        // rows ty, ty+16, ..., ty+240
    const int type = blockIdx.y;
    const int r0 = blockIdx.x * TM;
    const float* __restrict__ src = type ? X : (const float*)A;
    const float* __restrict__ wm  = type ? Wr : W;

    // staging index precompute
    const int arow = tid >> 3;            // +64 per it (4 its a 64 rows... idx>>3)
    const int aslot = (tid & 7) << 2;
    const int wrow = tid >> 5;
    const int wcol = (tid & 31) << 2;

    float4 ra[8], rw[4];
    // LOAD(kc=0)
#pragma unroll
    for (int it = 0; it < 8; ++it) {
        int row = arow + it * 32;         // (tid + it*256)>>3
        int gr = r0 + row;
        ra[it] = make_float4(0.f, 0.f, 0.f, 0.f);
        if (gr < NN) ra[it] = *(const float4*)(src + (size_t)gr * F + aslot);
    }
#pragma unroll
    for (int it = 0; it < 4; ++it) {
        int kr = wrow + it * 8;           // (tid + it*256)>>5
        rw[it] = *(const float4*)(wm + (size_t)kr * F + wcol);
    }

    float4 acc[16][2];
#pragma unroll
    for (int i = 0; i < 16; ++i) {
        acc[i][0] = make_float4(0.f, 0.f, 0.f, 0.f);
        acc[i][1] = make_float4(0.f, 0.f, 0.f, 0.f);
    }

    for (int kc = 0; kc < 4; ++kc) {
        __syncthreads();    // prev compute done reading LDS
        // STORE regs -> LDS
#pragma unroll
        for (int it = 0; it < 8; ++it)
            *(float4*)(&At[arow + it * 32][aslot]) = ra[it];
#pragma unroll
        for (int it = 0; it < 4; ++it)
            *(float4*)(&Wt[wrow + it * 8][wcol]) = rw[it];
        __syncthreads();
        // prefetch next chunk into regs (overlaps with compute below)
        if (kc < 3) {
            const int kb = (kc + 1) * TK;
#pragma unroll
            for (int it = 0; it < 8; ++it) {
                int row = arow + it * 32;
                int gr = r0 + row;
                ra[it] = make_float4(0.f, 0.f, 0.f, 0.f);
                if (gr < NN) ra[it] = *(const float4*)(src + (size_t)gr * F + kb + aslot);
            }
#pragma unroll
            for (int it = 0; it < 4; ++it) {
                int kr = wrow + it * 8;
                rw[it] = *(const float4*)(wm + (size_t)(kb + kr) * F + wcol);
            }
        }
        // COMPUTE chunk kc
#pragma unroll
        for (int kq = 0; kq < 8; ++kq) {
            float4 w0 = *(const float4*)(&Wt[kq * 4 + 0][tx * 8]);
            float4 w1 = *(const float4*)(&Wt[kq * 4 + 0][tx * 8 + 4]);
            float4 w2 = *(const float4*)(&Wt[kq * 4 + 1][tx * 8]);
            float4 w3 = *(const float4*)(&Wt[kq * 4 + 1][tx * 8 + 4]);
            float4 w4 = *(const float4*)(&Wt[kq * 4 + 2][tx * 8]);
            float4 w5 = *(const float4*)(&Wt[kq * 4 + 2][tx * 8 + 4]);
            float4 w6 = *(const float4*)(&Wt[kq * 4 + 3][tx * 8]);
            float4 w7 = *(const float4*)(&Wt[kq * 4 + 3][tx * 8 + 4]);
#pragma unroll
            for (int i = 0; i < 16; ++i) {
                float4 a = *(const float4*)(&At[ty + i * 16][kq * 4]);
                float4 c0 = acc[i][0], c1 = acc[i][1];
                c0.x = fmaf(a.x, w0.x, c0.x); c0.y = fmaf(a.x, w0.y, c0.y);
                c0.z = fmaf(a.x, w0.z, c0.z); c0.w = fmaf(a.x, w0.w, c0.w);
                c1.x = fmaf(a.x, w1.x, c1.x); c1.y = fmaf(a.x, w1.y, c1.y);
                c1.z = fmaf(a.x, w1.z, c1.z); c1.w = fmaf(a.x, w1.w, c1.w);
                c0.x = fmaf(a.y, w2.x, c0.x); c0.y = fmaf(a.y, w2.y, c0.y);
                c0.z = fmaf(a.y, w2.z, c0.z); c0.w = fmaf(a.y, w2.w, c0.w);
                c1.x = fmaf(a.y, w3.x, c1.x); c1.y = fmaf(a.y, w3.y, c1.y);
                c1.z = fmaf(a.y, w3.z, c1.z); c1.w = fmaf(a.y, w3.w, c1.w);
                c0.x = fmaf(a.z, w4.x, c0.x); c0.y = fmaf(a.z, w4.y, c0.y);
                c0.z = fmaf(a.z, w4.z, c0.z); c0.w = fmaf(a.z, w4.w, c0.w);
                c1.x = fmaf(a.z, w5.x, c1.x); c1.y = fmaf(a.z, w5.y, c1.y);
                c1.z = fmaf(a.z, w5.z, c1.z); c1.w = fmaf(a.z, w5.w, c1.w);
                c0.x = fmaf(a.w, w6.x, c0.x); c0.y = fmaf(a.w, w6.y, c0.y);
                c0.z = fmaf(a.w, w6.z, c0.z); c0.w = fmaf(a.w, w6.w, c0.w);
                c1.x = fmaf(a.w, w7.x, c1.x); c1.y = fmaf(a.w, w7.y, c1.y);
                c1.z = fmaf(a.w, w7.z, c1.z); c1.w = fmaf(a.w, w7.w, c1.w);
                acc[i][0] = c0; acc[i][1] = c1;
            }
        }
    }
    __syncthreads();

    if (type == 0) {
        float* ssum = &Wt[0][0];        // reuse weight LDS for stats (256 floats)
        float* ssq  = &Wt[0][0] + F;
        if (tid < 256) ((float*)&Wt[0][0])[tid] = 0.f;
        __syncthreads();
        float4 b0 = *(const float4*)(bias + tx * 8);
        float4 b1 = *(const float4*)(bias + tx * 8 + 4);
        float ls[8] = {0.f,0.f,0.f,0.f,0.f,0.f,0.f,0.f};
        float lq[8] = {0.f,0.f,0.f,0.f,0.f,0.f,0.f,0.f};
#pragma unroll
        for (int i = 0; i < 16; ++i) {
            int gr = r0 + ty + i * 16;
            if (gr < NN) {
                float r_[8];
                r_[0] = fmaxf(acc[i][0].x + b0.x, 0.f);
                r_[1] = fmaxf(acc[i][0].y + b0.y, 0.f);
                r_[2] = fmaxf(acc[i][0].z + b0.z, 0.f);
                r_[3] = fmaxf(acc[i][0].w + b0.w, 0.f);
                r_[4] = fmaxf(acc[i][1].x + b1.x, 0.f);
                r_[5] = fmaxf(acc[i][1].y + b1.y, 0.f);
                r_[6] = fmaxf(acc[i][1].z + b1.z, 0.f);
                r_[7] = fmaxf(acc[i][1].w + b1.w, 0.f);
#pragma unroll
                for (int j = 0; j < 8; ++j) {
                    ls[j] += r_[j];
                    lq[j] = fmaf(r_[j], r_[j], lq[j]);
                }
                *(float4*)(A + (size_t)gr * F + tx * 8)     = make_float4(r_[0], r_[1], r_[2], r_[3]);
                *(float4*)(A + (size_t)gr * F + tx * 8 + 4) = make_float4(r_[4], r_[5], r_[6], r_[7]);
            }
        }
#pragma unroll
        for (int j = 0; j < 8; ++j) {
            atomicAdd(&ssum[tx * 8 + j], ls[j]);
            atomicAdd(&ssq[tx * 8 + j], lq[j]);
        }
        __syncthreads();
        if (tid < F) {
            atomicAdd(&colsum[tid], ssum[tid]);
            atomicAdd(&colsq[tid], ssq[tid]);
        }
    } else {
        float4 b0 = *(const float4*)(biasr + tx * 8);
        float4 b1 = *(const float4*)(biasr + tx * 8 + 4);
#pragma unroll
        for (int i = 0; i < 16; ++i) {
            int gr = r0 + ty + i * 16;
            if (gr < NN) {
                *(float4*)(out + (size_t)gr * F + tx * 8) =
                    make_float4(acc[i][0].x + b0.x, acc[i][0].y + b0.y,
                                acc[i][0].z + b0.z, acc[i][0].w + b0.w);
                *(float4*)(out + (size_t)gr * F + tx * 8 + 4) =
                    make_float4(acc[i][1].x + b1.x, acc[i][1].y + b1.y,
                                acc[i][1].z + b1.z, acc[i][1].w + b1.w);
            }
        }
    }
}

__global__ void k_stats(const float* __restrict__ colsum, const float* __restrict__ colsq,
                        const float* __restrict__ gamma, const float* __restrict__ beta,
                        float* __restrict__ scale, float* __restrict__ shift)
{
    int c = threadIdx.x;
    if (c < F) {
        float inv_n = 1.0f / (float)NN;
        float mean = colsum[c] * inv_n;
        float ex2  = colsq[c] * inv_n;
        float var  = fmaxf(ex2 - mean * mean, 0.f);
        float d = var + BN_EPS;
        float is = rsqrtf(d);
        is = is * (1.5f - 0.5f * d * is * is);   // Newton refine
        float sc = gamma[c] * is;
        scale[c] = sc;
        shift[c] = beta[c] - sc * mean;
    }
}

// out = r*scale[c] + shift[c] + res   (res already in d_out)
__global__ __launch_bounds__(256) void k_final(const float* __restrict__ r,
                                               const float* __restrict__ scale,
                                               const float* __restrict__ shift,
                                               float* __restrict__ out)
{
    int idx = blockIdx.x * 256 + threadIdx.x;   // float4 index, 3.2M total (exact)
    int c4 = idx & 31;
    float4 rv = ((const float4*)r)[idx];
    float4 ov = ((float4*)out)[idx];
    float4 sv = ((const float4*)scale)[c4];
    float4 hv = ((const float4*)shift)[c4];
    float4 o;
    o.x = fmaf(rv.x, sv.x, hv.x) + ov.x;
    o.y = fmaf(rv.y, sv.y, hv.y) + ov.y;
    o.z = fmaf(rv.z, sv.z, hv.z) + ov.z;
    o.w = fmaf(rv.w, sv.w, hv.w) + ov.w;
    ((float4*)out)[idx] = o;
}

extern "C" void kernel_launch(void* const* d_in, const int* in_sizes, int n_in,
                              void* d_out, int out_size, void* d_ws, size_t ws_size,
                              hipStream_t stream)
{
    (void)in_sizes; (void)n_in; (void)out_size; (void)ws_size;
    const float* x     = (const float*)d_in[0];
    const void*  ei    = d_in[1];
    const float* W     = (const float*)d_in[2];
    const float* b     = (const float*)d_in[3];
    const float* gamma = (const float*)d_in[4];
    const float* beta  = (const float*)d_in[5];
    const float* Wres  = (const float*)d_in[6];
    const float* bres  = (const float*)d_in[7];
    float* out = (float*)d_out;

    char* w = (char*)d_ws;
    float* aggx   = (float*)(w + 0);            // 51,200,000 B
    int*   cnt    = (int*)  (w + 51200000);
    float* dinv   = (float*)(w + 51600128);
    int*   off    = (int*)  (w + 52000256);
    int*   cur    = (int*)  (w + 52400384);
    int*   csr    = (int*)  (w + 52800512);
    int*   bsum   = (int*)  (w + 55200512);
    int*   bbase  = (int*)  (w + 55202176);
    float* colsum = (float*)(w + 55203840);
    float* colsq  = (float*)(w + 55204352);
    float* scale  = (float*)(w + 55204864);
    float* shift  = (float*)(w + 55205376);
    int*   flag   = (int*)  (w + 55205888);

    const int G_INIT = 392;
    const int G_E    = (NE + 255) / 256;        // 2344
    const int G_N    = 391;
    const int G_AGG  = NN / 8;                  // 12500 exact
    const dim3 G_GEMM((NN + TM - 1) / TM, 2);   // (391, 2)
    const int G_FIN  = (NN * F / 4) / 256;      // 12500 exact

    k_init   <<<G_INIT, 256, 0, stream>>>((const unsigned*)ei, flag, cnt, colsum, colsq);
    k_count  <<<G_E, 256, 0, stream>>>(ei, flag, cnt);
    k_bsum   <<<G_N, 256, 0, stream>>>(cnt, bsum);
    k_bscan  <<<1, 512, 0, stream>>>(bsum, bbase);
    k_offsets<<<G_N, 256, 0, stream>>>(cnt, bbase, off, cur, dinv);
    k_place  <<<G_E, 256, 0, stream>>>(ei, flag, cur, csr);
    k_agg    <<<G_AGG, 256, 0, stream>>>(x, dinv, off, csr, aggx);
    k_gemm2  <<<G_GEMM, 256, 0, stream>>>(aggx, x, W, Wres, b, bres, out, colsum, colsq);
    k_stats  <<<1, 128, 0, stream>>>(colsum, colsq, gamma, beta, scale, shift);
    k_final  <<<G_FIN, 256, 0, stream>>>(aggx, scale, shift, out);
}

// Round 6
// 372.160 us; speedup vs baseline: 1.0809x; 1.0809x over previous
//
#include <hip/hip_runtime.h>

#define NN 100000
#define NE 600000
#define F  128
#define BN_EPS 1e-5f
#define TM 128
#define TK 32

// ---- init + detect int64 vs int32 edge_index (block 0 does detect) ----
__global__ void k_init(const unsigned* __restrict__ ei, int* __restrict__ flag,
                       int* __restrict__ cnt, float* __restrict__ colsum, float* __restrict__ colsq)
{
    int i = blockIdx.x * 256 + threadIdx.x;
    if (i <= NN) cnt[i] = 0;
    if (i < F) { colsum[i] = 0.f; colsq[i] = 0.f; }
    if (blockIdx.x == 0) {
        __shared__ int any;
        if (threadIdx.x == 0) any = 0;
        __syncthreads();
        unsigned v = ei[2 * threadIdx.x + 1];   // odd words: i64 high halves (0 if i64)
        if (v != 0u) atomicOr(&any, 1);
        __syncthreads();
        if (threadIdx.x == 0) *flag = (any == 0) ? 1 : 0;   // 1 => int64
    }
}

__global__ void k_count(const void* __restrict__ ei, const int* __restrict__ flag, int* __restrict__ cnt)
{
    int e = blockIdx.x * 256 + threadIdx.x;
    if (e >= NE) return;
    int col;
    if (*flag) col = (int)((const long long*)ei)[NE + e];
    else       col = ((const int*)ei)[NE + e];
    atomicAdd(&cnt[col], 1);
}

// ---- 3-kernel exclusive scan of cnt[0..NN] -> off[], cur[]; dinv fused ----
__global__ void k_bsum(const int* __restrict__ cnt, int* __restrict__ bsum)
{
    __shared__ int s[256];
    int b = blockIdx.x, t = threadIdx.x;
    int i = b * 256 + t;
    s[t] = (i <= NN) ? cnt[i] : 0;
    __syncthreads();
    for (int o = 128; o > 0; o >>= 1) {
        if (t < o) s[t] += s[t + o];
        __syncthreads();
    }
    if (t == 0) bsum[b] = s[0];
}

__global__ void k_bscan(const int* __restrict__ bsum, int* __restrict__ bbase)
{
    __shared__ int s[512];
    int t = threadIdx.x;
    int v = (t < 391) ? bsum[t] : 0;
    s[t] = v;
    __syncthreads();
    for (int o = 1; o < 512; o <<= 1) {
        int tmp = (t >= o) ? s[t - o] : 0;
        __syncthreads();
        s[t] += tmp;
        __syncthreads();
    }
    if (t < 391) bbase[t] = s[t] - v;   // exclusive
}

__global__ void k_offsets(const int* __restrict__ cnt, const int* __restrict__ bbase,
                          int* __restrict__ off, int* __restrict__ cur,
                          float* __restrict__ dinv)
{
    __shared__ int s[256];
    int b = blockIdx.x, t = threadIdx.x;
    int i = b * 256 + t;
    int v = (i <= NN) ? cnt[i] : 0;
    s[t] = v;
    __syncthreads();
    for (int o = 1; o < 256; o <<= 1) {
        int tmp = (t >= o) ? s[t - o] : 0;
        __syncthreads();
        s[t] += tmp;
        __syncthreads();
    }
    int excl = s[t] - v + bbase[b];
    if (i <= NN) {
        off[i] = excl;
        if (i < NN) {
            cur[i] = excl;
            float d = (float)(v + 1);           // +1 self-loop
            float r = rsqrtf(d);
            r = r * (1.5f - 0.5f * d * r * r);  // Newton refine
            dinv[i] = r;
        }
    }
}

__global__ void k_place(const void* __restrict__ ei, const int* __restrict__ flag,
                        int* __restrict__ cur, int* __restrict__ csr)
{
    int e = blockIdx.x * 256 + threadIdx.x;
    if (e >= NE) return;
    int row, col;
    if (*flag) {
        row = (int)((const long long*)ei)[e];
        col = (int)((const long long*)ei)[NE + e];
    } else {
        row = ((const int*)ei)[e];
        col = ((const int*)ei)[NE + e];
    }
    int slot = atomicAdd(&cur[col], 1);
    csr[slot] = row;
}

// ---- pull aggregation: one node per WAVE64; halves process even/odd edges of
//      the SAME node (no inter-half trip-count divergence), float4 per lane
//      -> 1KB / 2 edges per VMEM instr; unroll2 -> 2 loads in flight;
//      final cross-half merge via shfl_xor(32). ----
__global__ __launch_bounds__(256) void k_agg(const float* __restrict__ x, const float* __restrict__ dinv,
                                             const int* __restrict__ off, const int* __restrict__ csr,
                                             float* __restrict__ aggx)
{
    int node = blockIdx.x * 4 + (threadIdx.x >> 6);   // 25000 blocks * 4 waves = 100000 exact
    int lane = threadIdx.x & 63;
    int sub  = lane & 31;
    int half = lane >> 5;
    float ax = 0.f, ay = 0.f, az = 0.f, aw = 0.f;
    int e0 = off[node], e1 = off[node + 1];
    int e = e0 + half;                                // halves interleave edges
    for (; e + 2 < e1; e += 4) {                      // two per-lane iterations
        int r0 = csr[e], r1 = csr[e + 2];
        float s0 = dinv[r0], s1 = dinv[r1];
        float4 u0 = ((const float4*)(x + (size_t)r0 * F))[sub];
        float4 u1 = ((const float4*)(x + (size_t)r1 * F))[sub];
        ax = fmaf(u0.x, s0, ax); ay = fmaf(u0.y, s0, ay);
        az = fmaf(u0.z, s0, az); aw = fmaf(u0.w, s0, aw);
        ax = fmaf(u1.x, s1, ax); ay = fmaf(u1.y, s1, ay);
        az = fmaf(u1.z, s1, az); aw = fmaf(u1.w, s1, aw);
    }
    for (; e < e1; e += 2) {
        int r = csr[e]; float s = dinv[r];
        float4 u = ((const float4*)(x + (size_t)r * F))[sub];
        ax = fmaf(u.x, s, ax); ay = fmaf(u.y, s, ay);
        az = fmaf(u.z, s, az); aw = fmaf(u.w, s, aw);
    }
    // merge the two halves (lane i <-> lane i+32)
    ax += __shfl_xor(ax, 32); ay += __shfl_xor(ay, 32);
    az += __shfl_xor(az, 32); aw += __shfl_xor(aw, 32);
    if (half == 0) {
        float di = dinv[node];
        float4 v = ((const float4*)(x + (size_t)node * F))[sub];
        float4 o;
        o.x = (fmaf(v.x, di, ax)) * di;
        o.y = (fmaf(v.y, di, ay)) * di;
        o.z = (fmaf(v.z, di, az)) * di;
        o.w = (fmaf(v.w, di, aw)) * di;
        ((float4*)(aggx + (size_t)node * F))[sub] = o;
    }
}

// ---- GEMM: blockIdx.y==0 : r = relu(aggx@W + b) in-place into aggx, + BN partials
//            blockIdx.y==1 : out = x@Wr + br
// EXACT round-4 layout (tile 128x128, microtile 16x4, LDS 32KB, 0 conflicts,
// acc=64 VGPR) + register prefetch of next chunk (T14) to hide global latency
// at the 4 chunk boundaries. launch_bounds(256,2) caps VGPR at 128 (the
// occupancy cliff: >128 halves waves/SIMD — round 5's 184-VGPR lesson).
__global__ __launch_bounds__(256, 2) void k_gemm2(
    float* __restrict__ A, const float* __restrict__ X,
    const float* __restrict__ W, const float* __restrict__ Wr,
    const float* __restrict__ bias, const float* __restrict__ biasr,
    float* __restrict__ out, float* __restrict__ colsum, float* __restrict__ colsq)
{
    __shared__ float At[TM][TK];    // 16 KB
    __shared__ float Wt[TK][F];     // 16 KB

    const int tid = threadIdx.x;
    const int tx = tid & 31;        // cols 4*tx..+3  (contiguous row sweep: conflict-free)
    const int ty = tid >> 5;        // rows ty*16..+15 (2 addrs/wave: broadcast)
    const int type = blockIdx.y;
    const int r0 = blockIdx.x * TM;
    const float* __restrict__ src = type ? X : (const float*)A;
    const float* __restrict__ wm  = type ? Wr : W;

    // staging index precompute
    const int arow = tid >> 3;              // +32 per it
    const int aslot = (tid & 7) << 2;
    const int wrow = tid >> 5;              // +8 per it
    const int wcol = (tid & 31) << 2;

    float4 ra[4], rw[4];
    // LOAD chunk 0 into regs
#pragma unroll
    for (int it = 0; it < 4; ++it) {
        int gr = r0 + arow + it * 32;
        ra[it] = make_float4(0.f, 0.f, 0.f, 0.f);
        if (gr < NN) ra[it] = *(const float4*)(src + (size_t)gr * F + aslot);
    }
#pragma unroll
    for (int it = 0; it < 4; ++it)
        rw[it] = *(const float4*)(wm + (size_t)(wrow + it * 8) * F + wcol);

    float4 acc[16];
#pragma unroll
    for (int i = 0; i < 16; ++i) acc[i] = make_float4(0.f, 0.f, 0.f, 0.f);

    for (int kc = 0; kc < 4; ++kc) {
        __syncthreads();    // previous compute done reading LDS
        // STORE regs -> LDS
#pragma unroll
        for (int it = 0; it < 4; ++it)
            *(float4*)(&At[arow + it * 32][aslot]) = ra[it];
#pragma unroll
        for (int it = 0; it < 4; ++it)
            *(float4*)(&Wt[wrow + it * 8][wcol]) = rw[it];
        __syncthreads();
        // PREFETCH next chunk into regs (overlaps with compute below)
        if (kc < 3) {
            const int kb = (kc + 1) * TK;
#pragma unroll
            for (int it = 0; it < 4; ++it) {
                int gr = r0 + arow + it * 32;
                ra[it] = make_float4(0.f, 0.f, 0.f, 0.f);
                if (gr < NN) ra[it] = *(const float4*)(src + (size_t)gr * F + kb + aslot);
            }
#pragma unroll
            for (int it = 0; it < 4; ++it)
                rw[it] = *(const float4*)(wm + (size_t)(kb + wrow + it * 8) * F + wcol);
        }
        // COMPUTE chunk kc
#pragma unroll
        for (int kq = 0; kq < 8; ++kq) {
            float4 w0 = *(const float4*)(&Wt[kq * 4 + 0][tx * 4]);
            float4 w1 = *(const float4*)(&Wt[kq * 4 + 1][tx * 4]);
            float4 w2 = *(const float4*)(&Wt[kq * 4 + 2][tx * 4]);
            float4 w3 = *(const float4*)(&Wt[kq * 4 + 3][tx * 4]);
#pragma unroll
            for (int i = 0; i < 16; ++i) {
                float4 a = *(const float4*)(&At[ty * 16 + i][kq * 4]);
                acc[i].x = fmaf(a.x, w0.x, acc[i].x);
                acc[i].y = fmaf(a.x, w0.y, acc[i].y);
                acc[i].z = fmaf(a.x, w0.z, acc[i].z);
                acc[i].w = fmaf(a.x, w0.w, acc[i].w);
                acc[i].x = fmaf(a.y, w1.x, acc[i].x);
                acc[i].y = fmaf(a.y, w1.y, acc[i].y);
                acc[i].z = fmaf(a.y, w1.z, acc[i].z);
                acc[i].w = fmaf(a.y, w1.w, acc[i].w);
                acc[i].x = fmaf(a.z, w2.x, acc[i].x);
                acc[i].y = fmaf(a.z, w2.y, acc[i].y);
                acc[i].z = fmaf(a.z, w2.z, acc[i].z);
                acc[i].w = fmaf(a.z, w2.w, acc[i].w);
                acc[i].x = fmaf(a.w, w3.x, acc[i].x);
                acc[i].y = fmaf(a.w, w3.y, acc[i].y);
                acc[i].z = fmaf(a.w, w3.z, acc[i].z);
                acc[i].w = fmaf(a.w, w3.w, acc[i].w);
            }
        }
    }
    __syncthreads();

    if (type == 0) {
        float* ssum = &Wt[0][0];        // reuse weight LDS for stats
        float* ssq  = &Wt[0][0] + F;
        if (tid < 256) ((float*)&Wt[0][0])[tid] = 0.f;
        __syncthreads();
        float4 bv = *(const float4*)(bias + tx * 4);
        float ls[4] = {0.f, 0.f, 0.f, 0.f};
        float lq[4] = {0.f, 0.f, 0.f, 0.f};
#pragma unroll
        for (int i = 0; i < 16; ++i) {
            int gr = r0 + ty * 16 + i;
            if (gr < NN) {
                float r0_ = fmaxf(acc[i].x + bv.x, 0.f);
                float r1_ = fmaxf(acc[i].y + bv.y, 0.f);
                float r2_ = fmaxf(acc[i].z + bv.z, 0.f);
                float r3_ = fmaxf(acc[i].w + bv.w, 0.f);
                ls[0] += r0_; lq[0] = fmaf(r0_, r0_, lq[0]);
                ls[1] += r1_; lq[1] = fmaf(r1_, r1_, lq[1]);
                ls[2] += r2_; lq[2] = fmaf(r2_, r2_, lq[2]);
                ls[3] += r3_; lq[3] = fmaf(r3_, r3_, lq[3]);
                *(float4*)(A + (size_t)gr * F + tx * 4) = make_float4(r0_, r1_, r2_, r3_);
            }
        }
#pragma unroll
        for (int j = 0; j < 4; ++j) {
            atomicAdd(&ssum[tx * 4 + j], ls[j]);
            atomicAdd(&ssq[tx * 4 + j], lq[j]);
        }
        __syncthreads();
        if (tid < F) {
            atomicAdd(&colsum[tid], ssum[tid]);
            atomicAdd(&colsq[tid], ssq[tid]);
        }
    } else {
        float4 bv = *(const float4*)(biasr + tx * 4);
#pragma unroll
        for (int i = 0; i < 16; ++i) {
            int gr = r0 + ty * 16 + i;
            if (gr < NN) {
                *(float4*)(out + (size_t)gr * F + tx * 4) =
                    make_float4(acc[i].x + bv.x, acc[i].y + bv.y,
                                acc[i].z + bv.z, acc[i].w + bv.w);
            }
        }
    }
}

__global__ void k_stats(const float* __restrict__ colsum, const float* __restrict__ colsq,
                        const float* __restrict__ gamma, const float* __restrict__ beta,
                        float* __restrict__ scale, float* __restrict__ shift)
{
    int c = threadIdx.x;
    if (c < F) {
        float inv_n = 1.0f / (float)NN;
        float mean = colsum[c] * inv_n;
        float ex2  = colsq[c] * inv_n;
        float var  = fmaxf(ex2 - mean * mean, 0.f);
        float d = var + BN_EPS;
        float is = rsqrtf(d);
        is = is * (1.5f - 0.5f * d * is * is);   // Newton refine
        float sc = gamma[c] * is;
        scale[c] = sc;
        shift[c] = beta[c] - sc * mean;
    }
}

// out = r*scale[c] + shift[c] + res   (res already in d_out)
__global__ __launch_bounds__(256) void k_final(const float* __restrict__ r,
                                               const float* __restrict__ scale,
                                               const float* __restrict__ shift,
                                               float* __restrict__ out)
{
    int idx = blockIdx.x * 256 + threadIdx.x;   // float4 index, 3.2M total (exact)
    int c4 = idx & 31;
    float4 rv = ((const float4*)r)[idx];
    float4 ov = ((float4*)out)[idx];
    float4 sv = ((const float4*)scale)[c4];
    float4 hv = ((const float4*)shift)[c4];
    float4 o;
    o.x = fmaf(rv.x, sv.x, hv.x) + ov.x;
    o.y = fmaf(rv.y, sv.y, hv.y) + ov.y;
    o.z = fmaf(rv.z, sv.z, hv.z) + ov.z;
    o.w = fmaf(rv.w, sv.w, hv.w) + ov.w;
    ((float4*)out)[idx] = o;
}

extern "C" void kernel_launch(void* const* d_in, const int* in_sizes, int n_in,
                              void* d_out, int out_size, void* d_ws, size_t ws_size,
                              hipStream_t stream)
{
    (void)in_sizes; (void)n_in; (void)out_size; (void)ws_size;
    const float* x     = (const float*)d_in[0];
    const void*  ei    = d_in[1];
    const float* W     = (const float*)d_in[2];
    const float* b     = (const float*)d_in[3];
    const float* gamma = (const float*)d_in[4];
    const float* beta  = (const float*)d_in[5];
    const float* Wres  = (const float*)d_in[6];
    const float* bres  = (const float*)d_in[7];
    float* out = (float*)d_out;

    char* w = (char*)d_ws;
    float* aggx   = (float*)(w + 0);            // 51,200,000 B
    int*   cnt    = (int*)  (w + 51200000);
    float* dinv   = (float*)(w + 51600128);
    int*   off    = (int*)  (w + 52000256);
    int*   cur    = (int*)  (w + 52400384);
    int*   csr    = (int*)  (w + 52800512);
    int*   bsum   = (int*)  (w + 55200512);
    int*   bbase  = (int*)  (w + 55202176);
    float* colsum = (float*)(w + 55203840);
    float* colsq  = (float*)(w + 55204352);
    float* scale  = (float*)(w + 55204864);
    float* shift  = (float*)(w + 55205376);
    int*   flag   = (int*)  (w + 55205888);

    const int G_INIT = 392;
    const int G_E    = (NE + 255) / 256;        // 2344
    const int G_N    = 391;
    const int G_AGG  = NN / 4;                  // 25000 exact (4 waves/block, 1 node/wave)
    const dim3 G_GEMM((NN + TM - 1) / TM, 2);   // (782, 2)
    const int G_FIN  = (NN * F / 4) / 256;      // 12500 exact

    k_init   <<<G_INIT, 256, 0, stream>>>((const unsigned*)ei, flag, cnt, colsum, colsq);
    k_count  <<<G_E, 256, 0, stream>>>(ei, flag, cnt);
    k_bsum   <<<G_N, 256, 0, stream>>>(cnt, bsum);
    k_bscan  <<<1, 512, 0, stream>>>(bsum, bbase);
    k_offsets<<<G_N, 256, 0, stream>>>(cnt, bbase, off, cur, dinv);
    k_place  <<<G_E, 256, 0, stream>>>(ei, flag, cur, csr);
    k_agg    <<<G_AGG, 256, 0, stream>>>(x, dinv, off, csr, aggx);
    k_gemm2  <<<G_GEMM, 256, 0, stream>>>(aggx, x, W, Wres, b, bres, out, colsum, colsq);
    k_stats  <<<1, 128, 0, stream>>>(colsum, colsq, gamma, beta, scale, shift);
    k_final  <<<G_FIN, 256, 0, stream>>>(aggx, scale, shift, out);
}

// Round 7
// 318.563 us; speedup vs baseline: 1.2628x; 1.1682x over previous
//
#include <hip/hip_runtime.h>

#define NN 100000
#define NE 600000
#define F  128
#define BN_EPS 1e-5f
#define TM 128
#define TK 32

typedef short bf8 __attribute__((ext_vector_type(8)));
typedef float f32x4 __attribute__((ext_vector_type(4)));

__device__ __forceinline__ unsigned short bf16_rne(float x) {
    unsigned u = __float_as_uint(x);
    return (unsigned short)((u + 0x7FFFu + ((u >> 16) & 1u)) >> 16);
}
__device__ __forceinline__ void split_bf16(float x, unsigned short& h, unsigned short& l) {
    unsigned short hh = bf16_rne(x);
    float hf = __uint_as_float(((unsigned)hh) << 16);
    h = hh;
    l = bf16_rne(x - hf);
}

// ---- init + detect int64 vs int32 edge_index (block 0 does detect) ----
__global__ void k_init(const unsigned* __restrict__ ei, int* __restrict__ flag,
                       int* __restrict__ cnt, float* __restrict__ colsum, float* __restrict__ colsq)
{
    int i = blockIdx.x * 256 + threadIdx.x;
    if (i <= NN) cnt[i] = 0;
    if (i < F) { colsum[i] = 0.f; colsq[i] = 0.f; }
    if (blockIdx.x == 0) {
        __shared__ int any;
        if (threadIdx.x == 0) any = 0;
        __syncthreads();
        unsigned v = ei[2 * threadIdx.x + 1];   // odd words: i64 high halves (0 if i64)
        if (v != 0u) atomicOr(&any, 1);
        __syncthreads();
        if (threadIdx.x == 0) *flag = (any == 0) ? 1 : 0;   // 1 => int64
    }
}

__global__ void k_count(const void* __restrict__ ei, const int* __restrict__ flag, int* __restrict__ cnt)
{
    int e = blockIdx.x * 256 + threadIdx.x;
    if (e >= NE) return;
    int col;
    if (*flag) col = (int)((const long long*)ei)[NE + e];
    else       col = ((const int*)ei)[NE + e];
    atomicAdd(&cnt[col], 1);
}

// ---- 3-kernel exclusive scan of cnt[0..NN] -> off[], cur[]; dinv fused ----
__global__ void k_bsum(const int* __restrict__ cnt, int* __restrict__ bsum)
{
    __shared__ int s[256];
    int b = blockIdx.x, t = threadIdx.x;
    int i = b * 256 + t;
    s[t] = (i <= NN) ? cnt[i] : 0;
    __syncthreads();
    for (int o = 128; o > 0; o >>= 1) {
        if (t < o) s[t] += s[t + o];
        __syncthreads();
    }
    if (t == 0) bsum[b] = s[0];
}

__global__ void k_bscan(const int* __restrict__ bsum, int* __restrict__ bbase)
{
    __shared__ int s[512];
    int t = threadIdx.x;
    int v = (t < 391) ? bsum[t] : 0;
    s[t] = v;
    __syncthreads();
    for (int o = 1; o < 512; o <<= 1) {
        int tmp = (t >= o) ? s[t - o] : 0;
        __syncthreads();
        s[t] += tmp;
        __syncthreads();
    }
    if (t < 391) bbase[t] = s[t] - v;   // exclusive
}

__global__ void k_offsets(const int* __restrict__ cnt, const int* __restrict__ bbase,
                          int* __restrict__ off, int* __restrict__ cur,
                          float* __restrict__ dinv)
{
    __shared__ int s[256];
    int b = blockIdx.x, t = threadIdx.x;
    int i = b * 256 + t;
    int v = (i <= NN) ? cnt[i] : 0;
    s[t] = v;
    __syncthreads();
    for (int o = 1; o < 256; o <<= 1) {
        int tmp = (t >= o) ? s[t - o] : 0;
        __syncthreads();
        s[t] += tmp;
        __syncthreads();
    }
    int excl = s[t] - v + bbase[b];
    if (i <= NN) {
        off[i] = excl;
        if (i < NN) {
            cur[i] = excl;
            float d = (float)(v + 1);           // +1 self-loop
            float r = rsqrtf(d);
            r = r * (1.5f - 0.5f * d * r * r);  // Newton refine
            dinv[i] = r;
        }
    }
}

__global__ void k_place(const void* __restrict__ ei, const int* __restrict__ flag,
                        int* __restrict__ cur, int* __restrict__ csr)
{
    int e = blockIdx.x * 256 + threadIdx.x;
    if (e >= NE) return;
    int row, col;
    if (*flag) {
        row = (int)((const long long*)ei)[e];
        col = (int)((const long long*)ei)[NE + e];
    } else {
        row = ((const int*)ei)[e];
        col = ((const int*)ei)[NE + e];
    }
    int slot = atomicAdd(&cur[col], 1);
    csr[slot] = row;
}

// ---- repack W and Wres into MFMA-frag-major bf16 hi/lo layout ----
// entry t = ((type*4 + chunk)*8 + nfrag)*64 + lane ; 32 B per entry (16B hi, 16B lo)
// B-frag element: B[k = chunk*32 + 8*(lane>>4) + j][col = nfrag*16 + (lane&15)]
__global__ void k_wprep(const float* __restrict__ W, const float* __restrict__ Wr,
                        unsigned short* __restrict__ wprep)
{
    int t = blockIdx.x * 256 + threadIdx.x;      // 0..4095
    int lane = t & 63;
    int nf   = (t >> 6) & 7;
    int c    = (t >> 9) & 3;
    int type = t >> 11;
    const float* wsrc = type ? Wr : W;
    int col = nf * 16 + (lane & 15);
    int k0  = c * 32 + (lane >> 4) * 8;
    unsigned short hi[8], lo[8];
#pragma unroll
    for (int j = 0; j < 8; ++j)
        split_bf16(wsrc[(size_t)(k0 + j) * F + col], hi[j], lo[j]);
    unsigned short* dst = wprep + (size_t)t * 16;
#pragma unroll
    for (int j = 0; j < 8; ++j) { dst[j] = hi[j]; dst[8 + j] = lo[j]; }
}

// ---- pull aggregation: one node per WAVE64; halves interleave edges ----
__global__ __launch_bounds__(256) void k_agg(const float* __restrict__ x, const float* __restrict__ dinv,
                                             const int* __restrict__ off, const int* __restrict__ csr,
                                             float* __restrict__ aggx)
{
    int node = blockIdx.x * 4 + (threadIdx.x >> 6);
    int lane = threadIdx.x & 63;
    int sub  = lane & 31;
    int half = lane >> 5;
    float ax = 0.f, ay = 0.f, az = 0.f, aw = 0.f;
    int e0 = off[node], e1 = off[node + 1];
    int e = e0 + half;
    for (; e + 2 < e1; e += 4) {
        int r0 = csr[e], r1 = csr[e + 2];
        float s0 = dinv[r0], s1 = dinv[r1];
        float4 u0 = ((const float4*)(x + (size_t)r0 * F))[sub];
        float4 u1 = ((const float4*)(x + (size_t)r1 * F))[sub];
        ax = fmaf(u0.x, s0, ax); ay = fmaf(u0.y, s0, ay);
        az = fmaf(u0.z, s0, az); aw = fmaf(u0.w, s0, aw);
        ax = fmaf(u1.x, s1, ax); ay = fmaf(u1.y, s1, ay);
        az = fmaf(u1.z, s1, az); aw = fmaf(u1.w, s1, aw);
    }
    for (; e < e1; e += 2) {
        int r = csr[e]; float s = dinv[r];
        float4 u = ((const float4*)(x + (size_t)r * F))[sub];
        ax = fmaf(u.x, s, ax); ay = fmaf(u.y, s, ay);
        az = fmaf(u.z, s, az); aw = fmaf(u.w, s, aw);
    }
    ax += __shfl_xor(ax, 32); ay += __shfl_xor(ay, 32);
    az += __shfl_xor(az, 32); aw += __shfl_xor(aw, 32);
    if (half == 0) {
        float di = dinv[node];
        float4 v = ((const float4*)(x + (size_t)node * F))[sub];
        float4 o;
        o.x = (fmaf(v.x, di, ax)) * di;
        o.y = (fmaf(v.y, di, ay)) * di;
        o.z = (fmaf(v.z, di, az)) * di;
        o.w = (fmaf(v.w, di, aw)) * di;
        ((float4*)(aggx + (size_t)node * F))[sub] = o;
    }
}

// ---- MFMA GEMM via bf16 hi/lo split (3 passes: hi*hi + hi*lo + lo*hi) ----
// blockIdx.y==0 : r = relu(aggx@W + b) in-place into aggx, + BN partials
// blockIdx.y==1 : out = x@Wr + br
// 4 waves (2x2), each wave 64x64 out = 4x4 frags of mfma_f32_16x16x32_bf16.
// A: fp32 global -> split -> LDS [128][40] bf16 hi/lo (pad 40: 16B-aligned,
// conflict-light frag reads, 1 ds_read_b128 per frag). B: direct 16B global
// loads from wprep (L2-resident). Frag maps (m89-verified family):
//   A: row=lane&15, k=8*(lane>>4)+j ; B: col=lane&15, same k
//   D: col=lane&15, row=4*(lane>>4)+reg
__global__ __launch_bounds__(256) void k_gemm2(
    float* __restrict__ A, const float* __restrict__ X,
    const unsigned short* __restrict__ wprep,
    const float* __restrict__ bias, const float* __restrict__ biasr,
    float* __restrict__ out, float* __restrict__ colsum, float* __restrict__ colsq)
{
    __shared__ unsigned short Ahi[TM][40];   // 10 KB
    __shared__ unsigned short Alo[TM][40];   // 10 KB
    __shared__ float sstat[256];             // 1 KB (epilogue stats)

    const int tid  = threadIdx.x;
    const int type = blockIdx.y;
    const int r0   = blockIdx.x * TM;
    const float* __restrict__ src = type ? X : (const float*)A;

    const int lane = tid & 63;
    const int wv = tid >> 6;
    const int wr = wv >> 1;         // wave row half (64 rows)
    const int wc = wv & 1;          // wave col half (64 cols)
    const int l15 = lane & 15;
    const int lq4 = lane >> 4;      // 0..3
    const int k0  = lq4 * 8;

    const int arow  = tid >> 3;             // staging row (+32 per it)
    const int aslot = (tid & 7) << 2;       // staging k-slot (float4)

    float4 ra[4];
#pragma unroll
    for (int it = 0; it < 4; ++it) {
        int gr = r0 + arow + it * 32;
        ra[it] = make_float4(0.f, 0.f, 0.f, 0.f);
        if (gr < NN) ra[it] = *(const float4*)(src + (size_t)gr * F + aslot);
    }

    f32x4 acc[4][4];
#pragma unroll
    for (int m = 0; m < 4; ++m)
#pragma unroll
        for (int n = 0; n < 4; ++n) acc[m][n] = (f32x4){0.f, 0.f, 0.f, 0.f};

    for (int c = 0; c < 4; ++c) {
        __syncthreads();                    // readers of prev chunk done
        // split + store current chunk to LDS
#pragma unroll
        for (int it = 0; it < 4; ++it) {
            int row = arow + it * 32;
            unsigned short h0, h1, h2, h3, l0, l1, l2, l3;
            split_bf16(ra[it].x, h0, l0); split_bf16(ra[it].y, h1, l1);
            split_bf16(ra[it].z, h2, l2); split_bf16(ra[it].w, h3, l3);
            *(ushort4*)&Ahi[row][aslot] = make_ushort4(h0, h1, h2, h3);
            *(ushort4*)&Alo[row][aslot] = make_ushort4(l0, l1, l2, l3);
        }
        __syncthreads();
        // prefetch next chunk into regs (overlaps MFMA below)
        if (c < 3) {
            int kb = (c + 1) * TK;
#pragma unroll
            for (int it = 0; it < 4; ++it) {
                int gr = r0 + arow + it * 32;
                ra[it] = make_float4(0.f, 0.f, 0.f, 0.f);
                if (gr < NN) ra[it] = *(const float4*)(src + (size_t)gr * F + kb + aslot);
            }
        }
        // B frags for this chunk (global, L2-hot)
        bf8 bhi[4], blo[4];
#pragma unroll
        for (int n = 0; n < 4; ++n) {
            int entry = ((type * 4 + c) * 8 + wc * 4 + n) * 64 + lane;
            const bf8* pb = (const bf8*)(wprep + (size_t)entry * 16);
            bhi[n] = pb[0];
            blo[n] = pb[1];
        }
        // A frags + MFMA
#pragma unroll
        for (int m = 0; m < 4; ++m) {
            int row = wr * 64 + m * 16 + l15;
            bf8 ah = *(const bf8*)&Ahi[row][k0];
            bf8 al = *(const bf8*)&Alo[row][k0];
#pragma unroll
            for (int n = 0; n < 4; ++n) {
                acc[m][n] = __builtin_amdgcn_mfma_f32_16x16x32_bf16(ah, bhi[n], acc[m][n], 0, 0, 0);
                acc[m][n] = __builtin_amdgcn_mfma_f32_16x16x32_bf16(ah, blo[n], acc[m][n], 0, 0, 0);
                acc[m][n] = __builtin_amdgcn_mfma_f32_16x16x32_bf16(al, bhi[n], acc[m][n], 0, 0, 0);
            }
        }
    }
    __syncthreads();

    if (type == 0) {
        sstat[tid] = 0.f;
        __syncthreads();
        float bv[4];
#pragma unroll
        for (int n = 0; n < 4; ++n) bv[n] = bias[wc * 64 + n * 16 + l15];
        float ls[4] = {0.f, 0.f, 0.f, 0.f};
        float lq[4] = {0.f, 0.f, 0.f, 0.f};
#pragma unroll
        for (int m = 0; m < 4; ++m)
#pragma unroll
            for (int reg = 0; reg < 4; ++reg) {
                int gr = r0 + wr * 64 + m * 16 + lq4 * 4 + reg;
                if (gr < NN) {
#pragma unroll
                    for (int n = 0; n < 4; ++n) {
                        float r = fmaxf(acc[m][n][reg] + bv[n], 0.f);
                        A[(size_t)gr * F + wc * 64 + n * 16 + l15] = r;
                        ls[n] += r;
                        lq[n] = fmaf(r, r, lq[n]);
                    }
                }
            }
#pragma unroll
        for (int n = 0; n < 4; ++n) {
            int col = wc * 64 + n * 16 + l15;
            atomicAdd(&sstat[col], ls[n]);
            atomicAdd(&sstat[128 + col], lq[n]);
        }
        __syncthreads();
        if (tid < F) {
            atomicAdd(&colsum[tid], sstat[tid]);
            atomicAdd(&colsq[tid], sstat[128 + tid]);
        }
    } else {
        float bv[4];
#pragma unroll
        for (int n = 0; n < 4; ++n) bv[n] = biasr[wc * 64 + n * 16 + l15];
#pragma unroll
        for (int m = 0; m < 4; ++m)
#pragma unroll
            for (int reg = 0; reg < 4; ++reg) {
                int gr = r0 + wr * 64 + m * 16 + lq4 * 4 + reg;
                if (gr < NN) {
#pragma unroll
                    for (int n = 0; n < 4; ++n)
                        out[(size_t)gr * F + wc * 64 + n * 16 + l15] = acc[m][n][reg] + bv[n];
                }
            }
    }
}

__global__ void k_stats(const float* __restrict__ colsum, const float* __restrict__ colsq,
                        const float* __restrict__ gamma, const float* __restrict__ beta,
                        float* __restrict__ scale, float* __restrict__ shift)
{
    int c = threadIdx.x;
    if (c < F) {
        float inv_n = 1.0f / (float)NN;
        float mean = colsum[c] * inv_n;
        float ex2  = colsq[c] * inv_n;
        float var  = fmaxf(ex2 - mean * mean, 0.f);
        float d = var + BN_EPS;
        float is = rsqrtf(d);
        is = is * (1.5f - 0.5f * d * is * is);   // Newton refine
        float sc = gamma[c] * is;
        scale[c] = sc;
        shift[c] = beta[c] - sc * mean;
    }
}

// out = r*scale[c] + shift[c] + res   (res already in d_out)
__global__ __launch_bounds__(256) void k_final(const float* __restrict__ r,
                                               const float* __restrict__ scale,
                                               const float* __restrict__ shift,
                                               float* __restrict__ out)
{
    int idx = blockIdx.x * 256 + threadIdx.x;   // float4 index, 3.2M total (exact)
    int c4 = idx & 31;
    float4 rv = ((const float4*)r)[idx];
    float4 ov = ((float4*)out)[idx];
    float4 sv = ((const float4*)scale)[c4];
    float4 hv = ((const float4*)shift)[c4];
    float4 o;
    o.x = fmaf(rv.x, sv.x, hv.x) + ov.x;
    o.y = fmaf(rv.y, sv.y, hv.y) + ov.y;
    o.z = fmaf(rv.z, sv.z, hv.z) + ov.z;
    o.w = fmaf(rv.w, sv.w, hv.w) + ov.w;
    ((float4*)out)[idx] = o;
}

extern "C" void kernel_launch(void* const* d_in, const int* in_sizes, int n_in,
                              void* d_out, int out_size, void* d_ws, size_t ws_size,
                              hipStream_t stream)
{
    (void)in_sizes; (void)n_in; (void)out_size; (void)ws_size;
    const float* x     = (const float*)d_in[0];
    const void*  ei    = d_in[1];
    const float* W     = (const float*)d_in[2];
    const float* b     = (const float*)d_in[3];
    const float* gamma = (const float*)d_in[4];
    const float* beta  = (const float*)d_in[5];
    const float* Wres  = (const float*)d_in[6];
    const float* bres  = (const float*)d_in[7];
    float* out = (float*)d_out;

    char* w = (char*)d_ws;
    float* aggx   = (float*)(w + 0);            // 51,200,000 B
    int*   cnt    = (int*)  (w + 51200000);     // 400 KB; dead after k_offsets
    unsigned short* wprep = (unsigned short*)(w + 51200000);  // 128 KB, reuses cnt
    float* dinv   = (float*)(w + 51600128);
    int*   off    = (int*)  (w + 52000256);
    int*   cur    = (int*)  (w + 52400384);
    int*   csr    = (int*)  (w + 52800512);
    int*   bsum   = (int*)  (w + 55200512);
    int*   bbase  = (int*)  (w + 55202176);
    float* colsum = (float*)(w + 55203840);
    float* colsq  = (float*)(w + 55204352);
    float* scale  = (float*)(w + 55204864);
    float* shift  = (float*)(w + 55205376);
    int*   flag   = (int*)  (w + 55205888);

    const int G_INIT = 392;
    const int G_E    = (NE + 255) / 256;        // 2344
    const int G_N    = 391;
    const int G_AGG  = NN / 4;                  // 25000 exact
    const dim3 G_GEMM((NN + TM - 1) / TM, 2);   // (782, 2)
    const int G_FIN  = (NN * F / 4) / 256;      // 12500 exact

    k_init   <<<G_INIT, 256, 0, stream>>>((const unsigned*)ei, flag, cnt, colsum, colsq);
    k_count  <<<G_E, 256, 0, stream>>>(ei, flag, cnt);
    k_bsum   <<<G_N, 256, 0, stream>>>(cnt, bsum);
    k_bscan  <<<1, 512, 0, stream>>>(bsum, bbase);
    k_offsets<<<G_N, 256, 0, stream>>>(cnt, bbase, off, cur, dinv);
    k_place  <<<G_E, 256, 0, stream>>>(ei, flag, cur, csr);
    k_wprep  <<<16, 256, 0, stream>>>(W, Wres, wprep);    // AFTER k_offsets: overwrites cnt
    k_agg    <<<G_AGG, 256, 0, stream>>>(x, dinv, off, csr, aggx);
    k_gemm2  <<<G_GEMM, 256, 0, stream>>>(aggx, x, wprep, b, bres, out, colsum, colsq);
    k_stats  <<<1, 128, 0, stream>>>(colsum, colsq, gamma, beta, scale, shift);
    k_final  <<<G_FIN, 256, 0, stream>>>(aggx, scale, shift, out);
}

// Round 8
// 307.375 us; speedup vs baseline: 1.3088x; 1.0364x over previous
//
#include <hip/hip_runtime.h>

#define NN 100000
#define NE 600000
#define F  128
#define BN_EPS 1e-5f
#define TM 128
#define TK 32

typedef short bf8 __attribute__((ext_vector_type(8)));
typedef float f32x4 __attribute__((ext_vector_type(4)));

__device__ __forceinline__ unsigned short bf16_rne(float x) {
    unsigned u = __float_as_uint(x);
    return (unsigned short)((u + 0x7FFFu + ((u >> 16) & 1u)) >> 16);
}
__device__ __forceinline__ void split_bf16(float x, unsigned short& h, unsigned short& l) {
    unsigned short hh = bf16_rne(x);
    float hf = __uint_as_float(((unsigned)hh) << 16);
    h = hh;
    l = bf16_rne(x - hf);
}

// ---- init + detect int64 vs int32 edge_index (block 0 does detect) ----
__global__ void k_init(const unsigned* __restrict__ ei, int* __restrict__ flag,
                       int* __restrict__ cnt, float* __restrict__ colsum, float* __restrict__ colsq)
{
    int i = blockIdx.x * 256 + threadIdx.x;
    if (i <= NN) cnt[i] = 0;
    if (i < F) { colsum[i] = 0.f; colsq[i] = 0.f; }
    if (blockIdx.x == 0) {
        __shared__ int any;
        if (threadIdx.x == 0) any = 0;
        __syncthreads();
        unsigned v = ei[2 * threadIdx.x + 1];   // odd words: i64 high halves (0 if i64)
        if (v != 0u) atomicOr(&any, 1);
        __syncthreads();
        if (threadIdx.x == 0) *flag = (any == 0) ? 1 : 0;   // 1 => int64
    }
}

__global__ void k_count(const void* __restrict__ ei, const int* __restrict__ flag, int* __restrict__ cnt)
{
    int e = blockIdx.x * 256 + threadIdx.x;
    if (e >= NE) return;
    int col;
    if (*flag) col = (int)((const long long*)ei)[NE + e];
    else       col = ((const int*)ei)[NE + e];
    atomicAdd(&cnt[col], 1);
}

// ---- 3-kernel exclusive scan of cnt[0..NN] -> off[], cur[]; dinv fused ----
__global__ void k_bsum(const int* __restrict__ cnt, int* __restrict__ bsum)
{
    __shared__ int s[256];
    int b = blockIdx.x, t = threadIdx.x;
    int i = b * 256 + t;
    s[t] = (i <= NN) ? cnt[i] : 0;
    __syncthreads();
    for (int o = 128; o > 0; o >>= 1) {
        if (t < o) s[t] += s[t + o];
        __syncthreads();
    }
    if (t == 0) bsum[b] = s[0];
}

__global__ void k_bscan(const int* __restrict__ bsum, int* __restrict__ bbase)
{
    __shared__ int s[512];
    int t = threadIdx.x;
    int v = (t < 391) ? bsum[t] : 0;
    s[t] = v;
    __syncthreads();
    for (int o = 1; o < 512; o <<= 1) {
        int tmp = (t >= o) ? s[t - o] : 0;
        __syncthreads();
        s[t] += tmp;
        __syncthreads();
    }
    if (t < 391) bbase[t] = s[t] - v;   // exclusive
}

__global__ void k_offsets(const int* __restrict__ cnt, const int* __restrict__ bbase,
                          int* __restrict__ off, int* __restrict__ cur,
                          float* __restrict__ dinv)
{
    __shared__ int s[256];
    int b = blockIdx.x, t = threadIdx.x;
    int i = b * 256 + t;
    int v = (i <= NN) ? cnt[i] : 0;
    s[t] = v;
    __syncthreads();
    for (int o = 1; o < 256; o <<= 1) {
        int tmp = (t >= o) ? s[t - o] : 0;
        __syncthreads();
        s[t] += tmp;
        __syncthreads();
    }
    int excl = s[t] - v + bbase[b];
    if (i <= NN) {
        off[i] = excl;
        if (i < NN) {
            cur[i] = excl;
            float d = (float)(v + 1);           // +1 self-loop
            float r = rsqrtf(d);
            r = r * (1.5f - 0.5f * d * r * r);  // Newton refine
            dinv[i] = r;
        }
    }
}

__global__ void k_place(const void* __restrict__ ei, const int* __restrict__ flag,
                        int* __restrict__ cur, int* __restrict__ csr)
{
    int e = blockIdx.x * 256 + threadIdx.x;
    if (e >= NE) return;
    int row, col;
    if (*flag) {
        row = (int)((const long long*)ei)[e];
        col = (int)((const long long*)ei)[NE + e];
    } else {
        row = ((const int*)ei)[e];
        col = ((const int*)ei)[NE + e];
    }
    int slot = atomicAdd(&cur[col], 1);
    csr[slot] = row;
}

// ---- pull aggregation (one node per wave64, halves interleave edges) +
//      fused W-repack duty on blocks 0..15 (wprep lives in dead `cur` region) ----
// wprep entry t = ((type*4 + chunk)*8 + nfrag)*64 + lane ; 32 B (16B hi, 16B lo)
// B-frag element: B[k = chunk*32 + 8*(lane>>4) + j][col = nfrag*16 + (lane&15)]
__global__ __launch_bounds__(256) void k_agg(const float* __restrict__ x, const float* __restrict__ dinv,
                                             const int* __restrict__ off, const int* __restrict__ csr,
                                             float* __restrict__ aggx,
                                             const float* __restrict__ W, const float* __restrict__ Wr,
                                             unsigned short* __restrict__ wprep)
{
    int node = blockIdx.x * 4 + (threadIdx.x >> 6);
    int lane = threadIdx.x & 63;
    int sub  = lane & 31;
    int half = lane >> 5;
    float ax = 0.f, ay = 0.f, az = 0.f, aw = 0.f;
    int e0 = off[node], e1 = off[node + 1];
    int e = e0 + half;
    for (; e + 2 < e1; e += 4) {
        int r0 = csr[e], r1 = csr[e + 2];
        float s0 = dinv[r0], s1 = dinv[r1];
        float4 u0 = ((const float4*)(x + (size_t)r0 * F))[sub];
        float4 u1 = ((const float4*)(x + (size_t)r1 * F))[sub];
        ax = fmaf(u0.x, s0, ax); ay = fmaf(u0.y, s0, ay);
        az = fmaf(u0.z, s0, az); aw = fmaf(u0.w, s0, aw);
        ax = fmaf(u1.x, s1, ax); ay = fmaf(u1.y, s1, ay);
        az = fmaf(u1.z, s1, az); aw = fmaf(u1.w, s1, aw);
    }
    for (; e < e1; e += 2) {
        int r = csr[e]; float s = dinv[r];
        float4 u = ((const float4*)(x + (size_t)r * F))[sub];
        ax = fmaf(u.x, s, ax); ay = fmaf(u.y, s, ay);
        az = fmaf(u.z, s, az); aw = fmaf(u.w, s, aw);
    }
    ax += __shfl_xor(ax, 32); ay += __shfl_xor(ay, 32);
    az += __shfl_xor(az, 32); aw += __shfl_xor(aw, 32);
    if (half == 0) {
        float di = dinv[node];
        float4 v = ((const float4*)(x + (size_t)node * F))[sub];
        float4 o;
        o.x = (fmaf(v.x, di, ax)) * di;
        o.y = (fmaf(v.y, di, ay)) * di;
        o.z = (fmaf(v.z, di, az)) * di;
        o.w = (fmaf(v.w, di, aw)) * di;
        ((float4*)(aggx + (size_t)node * F))[sub] = o;
    }
    // fused wprep duty
    if (blockIdx.x < 16) {
        int t = blockIdx.x * 256 + threadIdx.x;      // 0..4095
        int wl  = t & 63;
        int nf  = (t >> 6) & 7;
        int c   = (t >> 9) & 3;
        int typ = t >> 11;
        const float* wsrc = typ ? Wr : W;
        int col = nf * 16 + (wl & 15);
        int k0  = c * 32 + (wl >> 4) * 8;
        unsigned short hi[8], lo[8];
#pragma unroll
        for (int j = 0; j < 8; ++j)
            split_bf16(wsrc[(size_t)(k0 + j) * F + col], hi[j], lo[j]);
        unsigned short* dst = wprep + (size_t)t * 16;
#pragma unroll
        for (int j = 0; j < 8; ++j) { dst[j] = hi[j]; dst[8 + j] = lo[j]; }
    }
}

// ---- MFMA GEMM via bf16 hi/lo split, counted-vmcnt pipeline ----
// blockIdx.y==0 : r = relu(aggx@W + b) in-place into aggx, + BN partials
// blockIdx.y==1 : out = x@Wr + br
// Raw s_barrier (no vmcnt drain) + manual lgkmcnt(0) for write-visibility.
// Issue order per chunk: ds_write ra(c) -> issue ra(c+1) -> barrier ->
// MFMA with B(c) in regs -> issue B(c+1). All waits counted, never drained.
__global__ __launch_bounds__(256, 2) void k_gemm2(
    float* __restrict__ A, const float* __restrict__ X,
    const unsigned short* __restrict__ wprep,
    const float* __restrict__ bias, const float* __restrict__ biasr,
    float* __restrict__ out, float* __restrict__ colsum, float* __restrict__ colsq)
{
    __shared__ unsigned short Ahi[TM][40];   // 10 KB
    __shared__ unsigned short Alo[TM][40];   // 10 KB
    __shared__ float sstat[256];             // 1 KB

    const int tid  = threadIdx.x;
    const int type = blockIdx.y;
    const int r0   = blockIdx.x * TM;
    const float* __restrict__ src = type ? X : (const float*)A;

    const int lane = tid & 63;
    const int wv = tid >> 6;
    const int wr = wv >> 1;
    const int wc = wv & 1;
    const int l15 = lane & 15;
    const int lq4 = lane >> 4;
    const int k0  = lq4 * 8;

    const int arow  = tid >> 3;
    const int aslot = (tid & 7) << 2;

    float4 ra[4];
#pragma unroll
    for (int it = 0; it < 4; ++it) {
        int gr = r0 + arow + it * 32;
        ra[it] = make_float4(0.f, 0.f, 0.f, 0.f);
        if (gr < NN) ra[it] = *(const float4*)(src + (size_t)gr * F + aslot);
    }
    bf8 bhi[4], blo[4];
#pragma unroll
    for (int n = 0; n < 4; ++n) {
        int entry = ((type * 4 + 0) * 8 + wc * 4 + n) * 64 + lane;
        const bf8* pb = (const bf8*)(wprep + (size_t)entry * 16);
        bhi[n] = pb[0];
        blo[n] = pb[1];
    }

    f32x4 acc[4][4];
#pragma unroll
    for (int m = 0; m < 4; ++m)
#pragma unroll
        for (int n = 0; n < 4; ++n) acc[m][n] = (f32x4){0.f, 0.f, 0.f, 0.f};

    for (int c = 0; c < 4; ++c) {
        __builtin_amdgcn_s_barrier();               // readers of prev chunk done
        __builtin_amdgcn_sched_barrier(0);
        // split + ds_write chunk c (compiler: vmcnt wait for ra(c) only, B(c) stays in flight)
#pragma unroll
        for (int it = 0; it < 4; ++it) {
            int row = arow + it * 32;
            unsigned short h0, h1, h2, h3, l0, l1, l2, l3;
            split_bf16(ra[it].x, h0, l0); split_bf16(ra[it].y, h1, l1);
            split_bf16(ra[it].z, h2, l2); split_bf16(ra[it].w, h3, l3);
            *(ushort4*)&Ahi[row][aslot] = make_ushort4(h0, h1, h2, h3);
            *(ushort4*)&Alo[row][aslot] = make_ushort4(l0, l1, l2, l3);
        }
        // issue ra(c+1) now — in flight across the barrier
        if (c < 3) {
            int kb = (c + 1) * TK;
#pragma unroll
            for (int it = 0; it < 4; ++it) {
                int gr = r0 + arow + it * 32;
                float4 t = make_float4(0.f, 0.f, 0.f, 0.f);
                if (gr < NN) t = *(const float4*)(src + (size_t)gr * F + kb + aslot);
                ra[it] = t;
            }
        }
        asm volatile("s_waitcnt lgkmcnt(0)" ::: "memory");   // ds_writes visible
        __builtin_amdgcn_s_barrier();
        __builtin_amdgcn_sched_barrier(0);
        // MFMA phase: B(c) already resident, A frags from LDS (lgkm auto-waits)
#pragma unroll
        for (int m = 0; m < 4; ++m) {
            int row = wr * 64 + m * 16 + l15;
            bf8 ah = *(const bf8*)&Ahi[row][k0];
            bf8 al = *(const bf8*)&Alo[row][k0];
#pragma unroll
            for (int n = 0; n < 4; ++n) {
                acc[m][n] = __builtin_amdgcn_mfma_f32_16x16x32_bf16(ah, bhi[n], acc[m][n], 0, 0, 0);
                acc[m][n] = __builtin_amdgcn_mfma_f32_16x16x32_bf16(ah, blo[n], acc[m][n], 0, 0, 0);
                acc[m][n] = __builtin_amdgcn_mfma_f32_16x16x32_bf16(al, bhi[n], acc[m][n], 0, 0, 0);
            }
        }
        // issue B(c+1) — overlaps next chunk's write phase + barriers
        if (c < 3) {
            int cc = c + 1;
#pragma unroll
            for (int n = 0; n < 4; ++n) {
                int entry = ((type * 4 + cc) * 8 + wc * 4 + n) * 64 + lane;
                const bf8* pb = (const bf8*)(wprep + (size_t)entry * 16);
                bhi[n] = pb[0];
                blo[n] = pb[1];
            }
        }
    }
    __syncthreads();

    if (type == 0) {
        sstat[tid] = 0.f;
        __syncthreads();
        float bv[4];
#pragma unroll
        for (int n = 0; n < 4; ++n) bv[n] = bias[wc * 64 + n * 16 + l15];
        float ls[4] = {0.f, 0.f, 0.f, 0.f};
        float lq[4] = {0.f, 0.f, 0.f, 0.f};
#pragma unroll
        for (int m = 0; m < 4; ++m)
#pragma unroll
            for (int reg = 0; reg < 4; ++reg) {
                int gr = r0 + wr * 64 + m * 16 + lq4 * 4 + reg;
                if (gr < NN) {
#pragma unroll
                    for (int n = 0; n < 4; ++n) {
                        float r = fmaxf(acc[m][n][reg] + bv[n], 0.f);
                        A[(size_t)gr * F + wc * 64 + n * 16 + l15] = r;
                        ls[n] += r;
                        lq[n] = fmaf(r, r, lq[n]);
                    }
                }
            }
        // reduce across the 4 lq4 groups (same col) before LDS atomics: 4x fewer
#pragma unroll
        for (int n = 0; n < 4; ++n) {
            ls[n] += __shfl_xor(ls[n], 16); ls[n] += __shfl_xor(ls[n], 32);
            lq[n] += __shfl_xor(lq[n], 16); lq[n] += __shfl_xor(lq[n], 32);
        }
        if (lane < 16) {
#pragma unroll
            for (int n = 0; n < 4; ++n) {
                int col = wc * 64 + n * 16 + l15;
                atomicAdd(&sstat[col], ls[n]);
                atomicAdd(&sstat[128 + col], lq[n]);
            }
        }
        __syncthreads();
        if (tid < F) {
            atomicAdd(&colsum[tid], sstat[tid]);
            atomicAdd(&colsq[tid], sstat[128 + tid]);
        }
    } else {
        float bv[4];
#pragma unroll
        for (int n = 0; n < 4; ++n) bv[n] = biasr[wc * 64 + n * 16 + l15];
#pragma unroll
        for (int m = 0; m < 4; ++m)
#pragma unroll
            for (int reg = 0; reg < 4; ++reg) {
                int gr = r0 + wr * 64 + m * 16 + lq4 * 4 + reg;
                if (gr < NN) {
#pragma unroll
                    for (int n = 0; n < 4; ++n)
                        out[(size_t)gr * F + wc * 64 + n * 16 + l15] = acc[m][n][reg] + bv[n];
                }
            }
    }
}

// ---- fused stats + final: every block computes scale/shift (tiny), then
//      out = r*scale[c] + shift[c] + res (res already in d_out) ----
__global__ __launch_bounds__(256) void k_final(const float* __restrict__ colsum,
                                               const float* __restrict__ colsq,
                                               const float* __restrict__ gamma,
                                               const float* __restrict__ beta,
                                               const float* __restrict__ r,
                                               float* __restrict__ out)
{
    __shared__ float s_sc[F], s_sh[F];
    int tid = threadIdx.x;
    if (tid < F) {
        float inv_n = 1.0f / (float)NN;
        float mean = colsum[tid] * inv_n;
        float ex2  = colsq[tid] * inv_n;
        float var  = fmaxf(ex2 - mean * mean, 0.f);
        float d = var + BN_EPS;
        float is = rsqrtf(d);
        is = is * (1.5f - 0.5f * d * is * is);   // Newton refine
        float sc = gamma[tid] * is;
        s_sc[tid] = sc;
        s_sh[tid] = beta[tid] - sc * mean;
    }
    __syncthreads();
    int idx = blockIdx.x * 256 + tid;            // float4 index, 3.2M total (exact)
    int c4 = idx & 31;
    float4 rv = ((const float4*)r)[idx];
    float4 ov = ((float4*)out)[idx];
    float4 sv = *(const float4*)&s_sc[c4 * 4];
    float4 hv = *(const float4*)&s_sh[c4 * 4];
    float4 o;
    o.x = fmaf(rv.x, sv.x, hv.x) + ov.x;
    o.y = fmaf(rv.y, sv.y, hv.y) + ov.y;
    o.z = fmaf(rv.z, sv.z, hv.z) + ov.z;
    o.w = fmaf(rv.w, sv.w, hv.w) + ov.w;
    ((float4*)out)[idx] = o;
}

extern "C" void kernel_launch(void* const* d_in, const int* in_sizes, int n_in,
                              void* d_out, int out_size, void* d_ws, size_t ws_size,
                              hipStream_t stream)
{
    (void)in_sizes; (void)n_in; (void)out_size; (void)ws_size;
    const float* x     = (const float*)d_in[0];
    const void*  ei    = d_in[1];
    const float* W     = (const float*)d_in[2];
    const float* b     = (const float*)d_in[3];
    const float* gamma = (const float*)d_in[4];
    const float* beta  = (const float*)d_in[5];
    const float* Wres  = (const float*)d_in[6];
    const float* bres  = (const float*)d_in[7];
    float* out = (float*)d_out;

    char* w = (char*)d_ws;
    float* aggx   = (float*)(w + 0);            // 51,200,000 B
    int*   cnt    = (int*)  (w + 51200000);
    float* dinv   = (float*)(w + 51600128);
    int*   off    = (int*)  (w + 52000256);
    int*   cur    = (int*)  (w + 52400384);     // dead after k_place
    unsigned short* wprep = (unsigned short*)(w + 52400384);  // 128 KB, reuses cur
    int*   csr    = (int*)  (w + 52800512);
    int*   bsum   = (int*)  (w + 55200512);
    int*   bbase  = (int*)  (w + 55202176);
    float* colsum = (float*)(w + 55203840);
    float* colsq  = (float*)(w + 55204352);
    int*   flag   = (int*)  (w + 55205888);

    const int G_INIT = 392;
    const int G_E    = (NE + 255) / 256;        // 2344
    const int G_N    = 391;
    const int G_AGG  = NN / 4;                  // 25000 exact
    const dim3 G_GEMM((NN + TM - 1) / TM, 2);   // (782, 2)
    const int G_FIN  = (NN * F / 4) / 256;      // 12500 exact

    k_init   <<<G_INIT, 256, 0, stream>>>((const unsigned*)ei, flag, cnt, colsum, colsq);
    k_count  <<<G_E, 256, 0, stream>>>(ei, flag, cnt);
    k_bsum   <<<G_N, 256, 0, stream>>>(cnt, bsum);
    k_bscan  <<<1, 512, 0, stream>>>(bsum, bbase);
    k_offsets<<<G_N, 256, 0, stream>>>(cnt, bbase, off, cur, dinv);
    k_place  <<<G_E, 256, 0, stream>>>(ei, flag, cur, csr);
    k_agg    <<<G_AGG, 256, 0, stream>>>(x, dinv, off, csr, aggx, W, Wres, wprep);
    k_gemm2  <<<G_GEMM, 256, 0, stream>>>(aggx, x, wprep, b, bres, out, colsum, colsq);
    k_final  <<<G_FIN, 256, 0, stream>>>(colsum, colsq, gamma, beta, aggx, out);
}

// Round 11
// 307.248 us; speedup vs baseline: 1.3093x; 1.0004x over previous
//
#include <hip/hip_runtime.h>

#define NN 100000
#define NE 600000
#define F  128
#define BN_EPS 1e-5f
#define TM 128
#define TK 32

typedef short bf8 __attribute__((ext_vector_type(8)));
typedef float f32x4 __attribute__((ext_vector_type(4)));

__device__ __forceinline__ unsigned short bf16_rne(float x) {
    unsigned u = __float_as_uint(x);
    return (unsigned short)((u + 0x7FFFu + ((u >> 16) & 1u)) >> 16);
}
__device__ __forceinline__ void split_bf16(float x, unsigned short& h, unsigned short& l) {
    unsigned short hh = bf16_rne(x);
    float hf = __uint_as_float(((unsigned)hh) << 16);
    h = hh;
    l = bf16_rne(x - hf);
}

// ---- init + detect int64 vs int32 edge_index (block 0 does detect) ----
__global__ void k_init(const unsigned* __restrict__ ei, int* __restrict__ flag,
                       int* __restrict__ cnt, float* __restrict__ colsum, float* __restrict__ colsq)
{
    int i = blockIdx.x * 256 + threadIdx.x;
    if (i <= NN) cnt[i] = 0;
    if (i < F) { colsum[i] = 0.f; colsq[i] = 0.f; }
    if (blockIdx.x == 0) {
        __shared__ int any;
        if (threadIdx.x == 0) any = 0;
        __syncthreads();
        unsigned v = ei[2 * threadIdx.x + 1];   // odd words: i64 high halves (0 if i64)
        if (v != 0u) atomicOr(&any, 1);
        __syncthreads();
        if (threadIdx.x == 0) *flag = (any == 0) ? 1 : 0;   // 1 => int64
    }
}

__global__ void k_count(const void* __restrict__ ei, const int* __restrict__ flag, int* __restrict__ cnt)
{
    int e = blockIdx.x * 256 + threadIdx.x;
    if (e >= NE) return;
    int col;
    if (*flag) col = (int)((const long long*)ei)[NE + e];
    else       col = ((const int*)ei)[NE + e];
    atomicAdd(&cnt[col], 1);
}

// ---- 3-kernel exclusive scan of cnt[0..NN] -> off[], cur[]; dinv fused ----
__global__ void k_bsum(const int* __restrict__ cnt, int* __restrict__ bsum)
{
    __shared__ int s[256];
    int b = blockIdx.x, t = threadIdx.x;
    int i = b * 256 + t;
    s[t] = (i <= NN) ? cnt[i] : 0;
    __syncthreads();
    for (int o = 128; o > 0; o >>= 1) {
        if (t < o) s[t] += s[t + o];
        __syncthreads();
    }
    if (t == 0) bsum[b] = s[0];
}

__global__ void k_bscan(const int* __restrict__ bsum, int* __restrict__ bbase)
{
    __shared__ int s[512];
    int t = threadIdx.x;
    int v = (t < 391) ? bsum[t] : 0;
    s[t] = v;
    __syncthreads();
    for (int o = 1; o < 512; o <<= 1) {
        int tmp = (t >= o) ? s[t - o] : 0;
        __syncthreads();
        s[t] += tmp;
        __syncthreads();
    }
    if (t < 391) bbase[t] = s[t] - v;   // exclusive
}

__global__ void k_offsets(const int* __restrict__ cnt, const int* __restrict__ bbase,
                          int* __restrict__ off, int* __restrict__ cur,
                          float* __restrict__ dinv)
{
    __shared__ int s[256];
    int b = blockIdx.x, t = threadIdx.x;
    int i = b * 256 + t;
    int v = (i <= NN) ? cnt[i] : 0;
    s[t] = v;
    __syncthreads();
    for (int o = 1; o < 256; o <<= 1) {
        int tmp = (t >= o) ? s[t - o] : 0;
        __syncthreads();
        s[t] += tmp;
        __syncthreads();
    }
    int excl = s[t] - v + bbase[b];
    if (i <= NN) {
        off[i] = excl;
        if (i < NN) {
            cur[i] = excl;
            float d = (float)(v + 1);           // +1 self-loop
            float r = rsqrtf(d);
            r = r * (1.5f - 0.5f * d * r * r);  // Newton refine
            dinv[i] = r;
        }
    }
}

__global__ void k_place(const void* __restrict__ ei, const int* __restrict__ flag,
                        int* __restrict__ cur, int* __restrict__ csr)
{
    int e = blockIdx.x * 256 + threadIdx.x;
    if (e >= NE) return;
    int row, col;
    if (*flag) {
        row = (int)((const long long*)ei)[e];
        col = (int)((const long long*)ei)[NE + e];
    } else {
        row = ((const int*)ei)[e];
        col = ((const int*)ei)[NE + e];
    }
    int slot = atomicAdd(&cur[col], 1);
    csr[slot] = row;
}

// ---- pull aggregation (one node per wave64, halves interleave edges, 4-deep MLP) +
//      fused W-repack duty on blocks 0..15 (wprep lives in dead `cur` region) ----
__global__ __launch_bounds__(256) void k_agg(const float* __restrict__ x, const float* __restrict__ dinv,
                                             const int* __restrict__ off, const int* __restrict__ csr,
                                             float* __restrict__ aggx,
                                             const float* __restrict__ W, const float* __restrict__ Wr,
                                             unsigned short* __restrict__ wprep)
{
    int node = blockIdx.x * 4 + (threadIdx.x >> 6);
    int lane = threadIdx.x & 63;
    int sub  = lane & 31;
    int half = lane >> 5;
    float ax = 0.f, ay = 0.f, az = 0.f, aw = 0.f;
    int e0 = off[node], e1 = off[node + 1];
    int e = e0 + half;
    for (; e + 6 < e1; e += 8) {                 // 4 edges per half in flight
        int r0 = csr[e], r1 = csr[e + 2], r2 = csr[e + 4], r3 = csr[e + 6];
        float s0 = dinv[r0], s1 = dinv[r1], s2 = dinv[r2], s3 = dinv[r3];
        float4 u0 = ((const float4*)(x + (size_t)r0 * F))[sub];
        float4 u1 = ((const float4*)(x + (size_t)r1 * F))[sub];
        float4 u2 = ((const float4*)(x + (size_t)r2 * F))[sub];
        float4 u3 = ((const float4*)(x + (size_t)r3 * F))[sub];
        ax = fmaf(u0.x, s0, ax); ay = fmaf(u0.y, s0, ay);
        az = fmaf(u0.z, s0, az); aw = fmaf(u0.w, s0, aw);
        ax = fmaf(u1.x, s1, ax); ay = fmaf(u1.y, s1, ay);
        az = fmaf(u1.z, s1, az); aw = fmaf(u1.w, s1, aw);
        ax = fmaf(u2.x, s2, ax); ay = fmaf(u2.y, s2, ay);
        az = fmaf(u2.z, s2, az); aw = fmaf(u2.w, s2, aw);
        ax = fmaf(u3.x, s3, ax); ay = fmaf(u3.y, s3, ay);
        az = fmaf(u3.z, s3, az); aw = fmaf(u3.w, s3, aw);
    }
    for (; e < e1; e += 2) {
        int r = csr[e]; float s = dinv[r];
        float4 u = ((const float4*)(x + (size_t)r * F))[sub];
        ax = fmaf(u.x, s, ax); ay = fmaf(u.y, s, ay);
        az = fmaf(u.z, s, az); aw = fmaf(u.w, s, aw);
    }
    ax += __shfl_xor(ax, 32); ay += __shfl_xor(ay, 32);
    az += __shfl_xor(az, 32); aw += __shfl_xor(aw, 32);
    if (half == 0) {
        float di = dinv[node];
        float4 v = ((const float4*)(x + (size_t)node * F))[sub];
        float4 o;
        o.x = (fmaf(v.x, di, ax)) * di;
        o.y = (fmaf(v.y, di, ay)) * di;
        o.z = (fmaf(v.z, di, az)) * di;
        o.w = (fmaf(v.w, di, aw)) * di;
        ((float4*)(aggx + (size_t)node * F))[sub] = o;
    }
    // fused wprep duty
    if (blockIdx.x < 16) {
        int t = blockIdx.x * 256 + threadIdx.x;      // 0..4095
        int wl  = t & 63;
        int nf  = (t >> 6) & 7;
        int c   = (t >> 9) & 3;
        int typ = t >> 11;
        const float* wsrc = typ ? Wr : W;
        int col = nf * 16 + (wl & 15);
        int k0  = c * 32 + (wl >> 4) * 8;
        unsigned short hi[8], lo[8];
#pragma unroll
        for (int j = 0; j < 8; ++j)
            split_bf16(wsrc[(size_t)(k0 + j) * F + col], hi[j], lo[j]);
        unsigned short* dst = wprep + (size_t)t * 16;
#pragma unroll
        for (int j = 0; j < 8; ++j) { dst[j] = hi[j]; dst[8 + j] = lo[j]; }
    }
}

// ---- MFMA GEMM, bf16 hi/lo split, double-buffered LDS (1 barrier/chunk),
//      vectorized epilogue via per-wave LDS transpose ----
// blockIdx.y==0 : r = relu(aggx@W + b) in-place into aggx, + BN partials
// blockIdx.y==1 : out = x@Wr + br
__global__ __launch_bounds__(256, 2) void k_gemm2(
    float* __restrict__ A, const float* __restrict__ X,
    const unsigned short* __restrict__ wprep,
    const float* __restrict__ bias, const float* __restrict__ biasr,
    float* __restrict__ out, float* __restrict__ colsum, float* __restrict__ colsq)
{
    __shared__ unsigned short Abuf[2][2][TM][40];   // [buf][hi/lo][row][k] = 40 KB
    __shared__ float sstat[256];                    // 1 KB

    const int tid  = threadIdx.x;
    const int type = blockIdx.y;
    const int r0   = blockIdx.x * TM;
    const float* __restrict__ src = type ? X : (const float*)A;

    const int lane = tid & 63;
    const int wv = tid >> 6;
    const int wr = wv >> 1;
    const int wc = wv & 1;
    const int l15 = lane & 15;
    const int lq4 = lane >> 4;
    const int k0  = lq4 * 8;

    const int arow  = tid >> 3;
    const int aslot = (tid & 7) << 2;

    float4 ra[4];
#pragma unroll
    for (int it = 0; it < 4; ++it) {
        int gr = r0 + arow + it * 32;
        ra[it] = make_float4(0.f, 0.f, 0.f, 0.f);
        if (gr < NN) ra[it] = *(const float4*)(src + (size_t)gr * F + aslot);
    }
    bf8 bhi[4], blo[4];
#pragma unroll
    for (int n = 0; n < 4; ++n) {
        int entry = ((type * 4 + 0) * 8 + wc * 4 + n) * 64 + lane;
        const bf8* pb = (const bf8*)(wprep + (size_t)entry * 16);
        bhi[n] = pb[0];
        blo[n] = pb[1];
    }
    // write chunk 0 -> buf 0
#pragma unroll
    for (int it = 0; it < 4; ++it) {
        int row = arow + it * 32;
        unsigned short h0, h1, h2, h3, l0, l1, l2, l3;
        split_bf16(ra[it].x, h0, l0); split_bf16(ra[it].y, h1, l1);
        split_bf16(ra[it].z, h2, l2); split_bf16(ra[it].w, h3, l3);
        *(ushort4*)&Abuf[0][0][row][aslot] = make_ushort4(h0, h1, h2, h3);
        *(ushort4*)&Abuf[0][1][row][aslot] = make_ushort4(l0, l1, l2, l3);
    }
    // issue ra(1)
#pragma unroll
    for (int it = 0; it < 4; ++it) {
        int gr = r0 + arow + it * 32;
        float4 t = make_float4(0.f, 0.f, 0.f, 0.f);
        if (gr < NN) t = *(const float4*)(src + (size_t)gr * F + TK + aslot);
        ra[it] = t;
    }
    asm volatile("s_waitcnt lgkmcnt(0)" ::: "memory");
    __builtin_amdgcn_s_barrier();
    __builtin_amdgcn_sched_barrier(0);

    f32x4 acc[4][4];
#pragma unroll
    for (int m = 0; m < 4; ++m)
#pragma unroll
        for (int n = 0; n < 4; ++n) acc[m][n] = (f32x4){0.f, 0.f, 0.f, 0.f};

#pragma unroll
    for (int c = 0; c < 4; ++c) {
        // stage chunk c+1 into the other buffer (no barrier needed: disjoint buf)
        if (c < 3) {
            int nb = (c + 1) & 1;
#pragma unroll
            for (int it = 0; it < 4; ++it) {
                int row = arow + it * 32;
                unsigned short h0, h1, h2, h3, l0, l1, l2, l3;
                split_bf16(ra[it].x, h0, l0); split_bf16(ra[it].y, h1, l1);
                split_bf16(ra[it].z, h2, l2); split_bf16(ra[it].w, h3, l3);
                *(ushort4*)&Abuf[nb][0][row][aslot] = make_ushort4(h0, h1, h2, h3);
                *(ushort4*)&Abuf[nb][1][row][aslot] = make_ushort4(l0, l1, l2, l3);
            }
            if (c < 2) {
                int kb = (c + 2) * TK;
#pragma unroll
                for (int it = 0; it < 4; ++it) {
                    int gr = r0 + arow + it * 32;
                    float4 t = make_float4(0.f, 0.f, 0.f, 0.f);
                    if (gr < NN) t = *(const float4*)(src + (size_t)gr * F + kb + aslot);
                    ra[it] = t;
                }
            }
        }
        // MFMA on buf[c&1] with B(c)
        int cb = c & 1;
#pragma unroll
        for (int m = 0; m < 4; ++m) {
            int row = wr * 64 + m * 16 + l15;
            bf8 ah = *(const bf8*)&Abuf[cb][0][row][k0];
            bf8 al = *(const bf8*)&Abuf[cb][1][row][k0];
#pragma unroll
            for (int n = 0; n < 4; ++n) {
                acc[m][n] = __builtin_amdgcn_mfma_f32_16x16x32_bf16(ah, bhi[n], acc[m][n], 0, 0, 0);
                acc[m][n] = __builtin_amdgcn_mfma_f32_16x16x32_bf16(ah, blo[n], acc[m][n], 0, 0, 0);
                acc[m][n] = __builtin_amdgcn_mfma_f32_16x16x32_bf16(al, bhi[n], acc[m][n], 0, 0, 0);
            }
        }
        // load B(c+1) after MFMA consumed B(c); in flight across the barrier
        if (c < 3) {
            int cc = c + 1;
#pragma unroll
            for (int n = 0; n < 4; ++n) {
                int entry = ((type * 4 + cc) * 8 + wc * 4 + n) * 64 + lane;
                const bf8* pb = (const bf8*)(wprep + (size_t)entry * 16);
                bhi[n] = pb[0];
                blo[n] = pb[1];
            }
            asm volatile("s_waitcnt lgkmcnt(0)" ::: "memory");   // own ds ops done
            __builtin_amdgcn_s_barrier();                        // buf[(c+1)&1] visible
            __builtin_amdgcn_sched_barrier(0);
        }
    }

    // ---- epilogue: per-wave LDS transpose -> float4 coalesced stores ----
    float* ep = (float*)Abuf + wv * 1104;        // 16 rows x 68 stride = 4416 B/wave; 4 waves use 17664 B, all inside buf0 (20480 B) — only buf1 was read by the last chunk
    float bv[4];
#pragma unroll
    for (int n = 0; n < 4; ++n) bv[n] = (type ? biasr : bias)[wc * 64 + n * 16 + l15];
    float ls[4] = {0.f, 0.f, 0.f, 0.f};
    float lq[4] = {0.f, 0.f, 0.f, 0.f};
    float* dstm = type ? out : A;

#pragma unroll
    for (int m = 0; m < 4; ++m) {
        asm volatile("s_waitcnt lgkmcnt(0)" ::: "memory");
        __builtin_amdgcn_sched_barrier(0);
#pragma unroll
        for (int n = 0; n < 4; ++n)
#pragma unroll
            for (int reg = 0; reg < 4; ++reg) {
                float r = acc[m][n][reg] + bv[n];
                if (type == 0) {
                    r = fmaxf(r, 0.f);
                    ls[n] += r;
                    lq[n] = fmaf(r, r, lq[n]);
                }
                ep[(lq4 * 4 + reg) * 68 + n * 16 + l15] = r;
            }
        asm volatile("s_waitcnt lgkmcnt(0)" ::: "memory");
        __builtin_amdgcn_sched_barrier(0);
        int row = lane >> 2;
        int gr = r0 + wr * 64 + m * 16 + row;
#pragma unroll
        for (int j = 0; j < 4; ++j) {
            int col = ((lane & 3) + 4 * j) * 4;
            float4 v = *(float4*)&ep[row * 68 + col];
            if (gr < NN)
                *(float4*)(dstm + (size_t)gr * F + wc * 64 + col) = v;
        }
    }

    if (type == 0) {
        sstat[tid] = 0.f;
        __syncthreads();
#pragma unroll
        for (int n = 0; n < 4; ++n) {
            ls[n] += __shfl_xor(ls[n], 16); ls[n] += __shfl_xor(ls[n], 32);
            lq[n] += __shfl_xor(lq[n], 16); lq[n] += __shfl_xor(lq[n], 32);
        }
        if (lane < 16) {
#pragma unroll
            for (int n = 0; n < 4; ++n) {
                int col = wc * 64 + n * 16 + l15;
                atomicAdd(&sstat[col], ls[n]);
                atomicAdd(&sstat[128 + col], lq[n]);
            }
        }
        __syncthreads();
        if (tid < F) {
            atomicAdd(&colsum[tid], sstat[tid]);
            atomicAdd(&colsq[tid], sstat[128 + tid]);
        }
    }
}

// ---- fused stats + final: every block computes scale/shift (tiny), then
//      out = r*scale[c] + shift[c] + res (res already in d_out) ----
__global__ __launch_bounds__(256) void k_final(const float* __restrict__ colsum,
                                               const float* __restrict__ colsq,
                                               const float* __restrict__ gamma,
                                               const float* __restrict__ beta,
                                               const float* __restrict__ r,
                                               float* __restrict__ out)
{
    __shared__ float s_sc[F], s_sh[F];
    int tid = threadIdx.x;
    if (tid < F) {
        float inv_n = 1.0f / (float)NN;
        float mean = colsum[tid] * inv_n;
        float ex2  = colsq[tid] * inv_n;
        float var  = fmaxf(ex2 - mean * mean, 0.f);
        float d = var + BN_EPS;
        float is = rsqrtf(d);
        is = is * (1.5f - 0.5f * d * is * is);   // Newton refine
        float sc = gamma[tid] * is;
        s_sc[tid] = sc;
        s_sh[tid] = beta[tid] - sc * mean;
    }
    __syncthreads();
    int idx = blockIdx.x * 256 + tid;            // float4 index, 3.2M total (exact)
    int c4 = idx & 31;
    float4 rv = ((const float4*)r)[idx];
    float4 ov = ((float4*)out)[idx];
    float4 sv = *(const float4*)&s_sc[c4 * 4];
    float4 hv = *(const float4*)&s_sh[c4 * 4];
    float4 o;
    o.x = fmaf(rv.x, sv.x, hv.x) + ov.x;
    o.y = fmaf(rv.y, sv.y, hv.y) + ov.y;
    o.z = fmaf(rv.z, sv.z, hv.z) + ov.z;
    o.w = fmaf(rv.w, sv.w, hv.w) + ov.w;
    ((float4*)out)[idx] = o;
}

extern "C" void kernel_launch(void* const* d_in, const int* in_sizes, int n_in,
                              void* d_out, int out_size, void* d_ws, size_t ws_size,
                              hipStream_t stream)
{
    (void)in_sizes; (void)n_in; (void)out_size; (void)ws_size;
    const float* x     = (const float*)d_in[0];
    const void*  ei    = d_in[1];
    const float* W     = (const float*)d_in[2];
    const float* b     = (const float*)d_in[3];
    const float* gamma = (const float*)d_in[4];
    const float* beta  = (const float*)d_in[5];
    const float* Wres  = (const float*)d_in[6];
    const float* bres  = (const float*)d_in[7];
    float* out = (float*)d_out;

    char* w = (char*)d_ws;
    float* aggx   = (float*)(w + 0);            // 51,200,000 B
    int*   cnt    = (int*)  (w + 51200000);
    float* dinv   = (float*)(w + 51600128);
    int*   off    = (int*)  (w + 52000256);
    int*   cur    = (int*)  (w + 52400384);     // dead after k_place
    unsigned short* wprep = (unsigned short*)(w + 52400384);  // 128 KB, reuses cur
    int*   csr    = (int*)  (w + 52800512);
    int*   bsum   = (int*)  (w + 55200512);
    int*   bbase  = (int*)  (w + 55202176);
    float* colsum = (float*)(w + 55203840);
    float* colsq  = (float*)(w + 55204352);
    int*   flag   = (int*)  (w + 55205888);

    const int G_INIT = 392;
    const int G_E    = (NE + 255) / 256;        // 2344
    const int G_N    = 391;
    const int G_AGG  = NN / 4;                  // 25000 exact
    const dim3 G_GEMM((NN + TM - 1) / TM, 2);   // (782, 2)
    const int G_FIN  = (NN * F / 4) / 256;      // 12500 exact

    k_init   <<<G_INIT, 256, 0, stream>>>((const unsigned*)ei, flag, cnt, colsum, colsq);
    k_count  <<<G_E, 256, 0, stream>>>(ei, flag, cnt);
    k_bsum   <<<G_N, 256, 0, stream>>>(cnt, bsum);
    k_bscan  <<<1, 512, 0, stream>>>(bsum, bbase);
    k_offsets<<<G_N, 256, 0, stream>>>(cnt, bbase, off, cur, dinv);
    k_place  <<<G_E, 256, 0, stream>>>(ei, flag, cur, csr);
    k_agg    <<<G_AGG, 256, 0, stream>>>(x, dinv, off, csr, aggx, W, Wres, wprep);
    k_gemm2  <<<G_GEMM, 256, 0, stream>>>(aggx, x, wprep, b, bres, out, colsum, colsq);
    k_final  <<<G_FIN, 256, 0, stream>>>(colsum, colsq, gamma, beta, aggx, out);
}